// Round 5
// baseline (911.233 us; speedup 1.0000x reference)
//
#include <hip/hip_runtime.h>
#include <stdint.h>

// Problem constants (fixed by reference)
#define BB 8
#define NN 20000
#define CC 256
#define EE 320000
#define KK 3
#define MROWS (BB * NN)   // 160000
#define ROWU (BB * CC)    // 2048 ushorts per node-group (4 KB)

// ---------- bf16 helpers (raw ushort representation) ----------
__device__ __forceinline__ float bf2f(ushort u) {
    union { uint32_t ui; float f; } v; v.ui = ((uint32_t)u) << 16; return v.f;
}
__device__ __forceinline__ ushort f2bf(float f) {
    union { uint32_t ui; float f; } v; v.f = f;
    uint32_t r = (v.ui + 0x7FFFu + ((v.ui >> 16) & 1u)) >> 16;
    return (ushort)r;
}

typedef __bf16 bf16x8 __attribute__((ext_vector_type(8)));
typedef float  f32x4  __attribute__((ext_vector_type(4)));

__device__ __forceinline__ void gload16(const void* gptr, void* lptr) {
    __builtin_amdgcn_global_load_lds(
        (const __attribute__((address_space(1))) void*)gptr,
        (__attribute__((address_space(3))) void*)lptr, 16, 0, 0);
}

// ---------- edge width detect (FALLBACK ONLY when in_sizes is ambiguous) ----------
__global__ void detect_k(const int* __restrict__ raw, int* __restrict__ flag) {
    int i = blockIdx.x * 256 + threadIdx.x;
    int v = 0;
    int idx = 2 * i + 1;
    if (i < EE) v = raw[idx];            // odd 32-bit word in [0, 2E)
    unsigned long long m = __ballot(v != 0);
    if ((threadIdx.x & 63) == 0 && m) atomicOr(flag, 1);
}

// fused: normalize edges to int32 src[]/dst[] + degree counts (one pass)
// mode: 1 = int32, 2 = int64, 0 = read flag (device-detected fallback)
__global__ void convcount_k(const int* __restrict__ raw, const int* __restrict__ flag,
                            int mode,
                            int* __restrict__ src, int* __restrict__ dst,
                            int* __restrict__ deg_out, int* __restrict__ cnt_in) {
    int e = blockIdx.x * 256 + threadIdx.x;
    if (e >= EE) return;
    int m = mode ? mode : (*flag ? 1 : 2);   // flag!=0 -> genuine int32 data
    int s, d;
    if (m == 2) { s = raw[2 * e]; d = raw[2 * EE + 2 * e]; }   // int64 low words
    else        { s = raw[e];     d = raw[EE + e]; }            // int32
    src[e] = s; dst[e] = d;
    atomicAdd(&deg_out[s], 1);
    atomicAdd(&cnt_in[d], 1);
}

// single-block scan, shfl-based: thread t owns 20 contiguous elements.
__global__ void __launch_bounds__(1024) scan_k(const int* __restrict__ cnt_in,
                                               const int* __restrict__ deg_out,
                                               int* __restrict__ row_ptr,
                                               float* __restrict__ dis) {
    __shared__ int wpart[16];
    const int t = threadIdx.x;
    const int lane = t & 63, wid = t >> 6;
    const int base = t * 20;
    int local[20];
    int sum = 0;
#pragma unroll
    for (int i = 0; i < 20; i++) {
        int idx = base + i;
        int v = (idx < NN) ? cnt_in[idx] : 0;
        local[i] = sum;
        sum += v;
    }
    int sc = sum;  // inclusive wave scan of per-thread sums
#pragma unroll
    for (int off = 1; off < 64; off <<= 1) {
        int u = __shfl_up(sc, off, 64);
        if (lane >= off) sc += u;
    }
    if (lane == 63) wpart[wid] = sc;
    __syncthreads();
    if (wid == 0 && lane < 16) {
        int v = wpart[lane];
#pragma unroll
        for (int off = 1; off < 16; off <<= 1) {
            int u = __shfl_up(v, off, 64);
            if (lane >= off) v += u;
        }
        wpart[lane] = v;
    }
    __syncthreads();
    int wbase = (wid > 0) ? wpart[wid - 1] : 0;
    int tbase = wbase + sc - sum;  // exclusive base for this thread
#pragma unroll
    for (int i = 0; i < 20; i++) {
        int idx = base + i;
        if (idx < NN) row_ptr[idx] = tbase + local[i];
    }
    if (t == 1023) row_ptr[NN] = tbase + sum;
    for (int i = t; i < NN; i += 1024) {
        int d = deg_out[i];
        dis[i] = (d > 0) ? rsqrtf((float)d) : 0.0f;
    }
}

// packed (col, weight-bits) per CSR slot: one 8-B store instead of two 4-B scatters
__global__ void fill_k(const int* __restrict__ src, const int* __restrict__ dst,
                       const int* __restrict__ row_ptr, int* __restrict__ fillc,
                       const float* __restrict__ dis,
                       int2* __restrict__ cw) {
    int e = blockIdx.x * 256 + threadIdx.x;
    if (e >= EE) return;
    int s = src[e], d = dst[e];
    int pos = row_ptr[d] + atomicAdd(&fillc[d], 1);
    cw[pos] = make_int2(s, __float_as_int(-dis[s] * dis[d]));
}

// fused: fp32 [b,n,c] -> bf16 node-major [n,b,c]  (blocks 0..39999)
//      + WcatT prep                               (blocks 40000..40767)
// WcatT[n][k] bf16, n in [0,256), k in [0,768):
//   block 0: W1[0]-W1[2], block 1: W1[1], block 2: 2*W1[2]   (Tx2 = 2*P2 - Tx0 folded)
__global__ void cvtwprep_k(const float* __restrict__ x, ushort* __restrict__ y,
                           const float* __restrict__ W, ushort* __restrict__ wt) {
    int bid = blockIdx.x;
    if (bid < MROWS * CC / 1024) {
        size_t idx = ((size_t)bid * 256 + threadIdx.x) * 4;
        int row = (int)(idx >> 8);     // b*N + n  (< 160000)
        int c = (int)(idx & 255);
        int b = row / NN, n = row - b * NN;
        float4 v = *(const float4*)(x + idx);
        ushort4 o = make_ushort4(f2bf(v.x), f2bf(v.y), f2bf(v.z), f2bf(v.w));
        *(ushort4*)(y + ((size_t)(n * BB + b) * CC + c)) = o;
    } else {
        int idx = (bid - MROWS * CC / 1024) * 256 + threadIdx.x;
        if (idx >= 256 * 768) return;
        int n = idx / 768, k = idx % 768;
        int sel = k >> 8, kk = k & 255;
        const float* W1 = W + KK * CC * CC;  // layer 1
        float v;
        if (sel == 0)      v = W1[kk * CC + n] - W1[2 * CC * CC + kk * CC + n];
        else if (sel == 1) v = W1[CC * CC + kk * CC + n];
        else               v = 2.0f * W1[2 * CC * CC + kk * CC + n];
        wt[idx] = f2bf(v);
    }
}

// Node-major prop: y[n, :, :] = sum_{e: dst=n} w[e] * x[col[e], :, :]
// one 256-thread block per dst node; thread t covers bytes [t*16, t*16+16)
// of the 4 KB node-group. Edge loop unrolled by 4 for MLP.
// (unroll-8 measured NULL: same 196 us at occupancy 52% vs 70% -> fetch-path wall,
//  not ILP/occupancy. Keep the 24-VGPR unroll-4 form.)
__global__ void __launch_bounds__(256) prop_k(const ushort* __restrict__ x,
                                              ushort* __restrict__ y,
                                              const int* __restrict__ row_ptr,
                                              const int2* __restrict__ cw) {
    const int n = blockIdx.x;
    const int t = threadIdx.x;
    const int beg = row_ptr[n], end = row_ptr[n + 1];
    const ushort* xb = x + t * 8;   // 8 ushorts = 16 B per thread
    float a0 = 0, a1 = 0, a2 = 0, a3 = 0, a4 = 0, a5 = 0, a6 = 0, a7 = 0;
    int j = beg;
    for (; j + 4 <= end; j += 4) {
        int2 e0 = cw[j], e1 = cw[j + 1], e2 = cw[j + 2], e3 = cw[j + 3];
        int s0 = e0.x, s1 = e1.x, s2 = e2.x, s3 = e3.x;
        float w0 = __int_as_float(e0.y), w1 = __int_as_float(e1.y);
        float w2 = __int_as_float(e2.y), w3 = __int_as_float(e3.y);
        uint4 v0 = *(const uint4*)(xb + (size_t)s0 * ROWU);
        uint4 v1 = *(const uint4*)(xb + (size_t)s1 * ROWU);
        uint4 v2 = *(const uint4*)(xb + (size_t)s2 * ROWU);
        uint4 v3 = *(const uint4*)(xb + (size_t)s3 * ROWU);
        a0 += w0 * bf2f((ushort)v0.x) + w1 * bf2f((ushort)v1.x) + w2 * bf2f((ushort)v2.x) + w3 * bf2f((ushort)v3.x);
        a1 += w0 * bf2f((ushort)(v0.x >> 16)) + w1 * bf2f((ushort)(v1.x >> 16)) + w2 * bf2f((ushort)(v2.x >> 16)) + w3 * bf2f((ushort)(v3.x >> 16));
        a2 += w0 * bf2f((ushort)v0.y) + w1 * bf2f((ushort)v1.y) + w2 * bf2f((ushort)v2.y) + w3 * bf2f((ushort)v3.y);
        a3 += w0 * bf2f((ushort)(v0.y >> 16)) + w1 * bf2f((ushort)(v1.y >> 16)) + w2 * bf2f((ushort)(v2.y >> 16)) + w3 * bf2f((ushort)(v3.y >> 16));
        a4 += w0 * bf2f((ushort)v0.z) + w1 * bf2f((ushort)v1.z) + w2 * bf2f((ushort)v2.z) + w3 * bf2f((ushort)v3.z);
        a5 += w0 * bf2f((ushort)(v0.z >> 16)) + w1 * bf2f((ushort)(v1.z >> 16)) + w2 * bf2f((ushort)(v2.z >> 16)) + w3 * bf2f((ushort)(v3.z >> 16));
        a6 += w0 * bf2f((ushort)v0.w) + w1 * bf2f((ushort)v1.w) + w2 * bf2f((ushort)v2.w) + w3 * bf2f((ushort)v3.w);
        a7 += w0 * bf2f((ushort)(v0.w >> 16)) + w1 * bf2f((ushort)(v1.w >> 16)) + w2 * bf2f((ushort)(v2.w >> 16)) + w3 * bf2f((ushort)(v3.w >> 16));
    }
    for (; j < end; j++) {
        int2 e0 = cw[j];
        int s = e0.x;
        float wt = __int_as_float(e0.y);
        uint4 v = *(const uint4*)(xb + (size_t)s * ROWU);
        a0 += wt * bf2f((ushort)v.x);
        a1 += wt * bf2f((ushort)(v.x >> 16));
        a2 += wt * bf2f((ushort)v.y);
        a3 += wt * bf2f((ushort)(v.y >> 16));
        a4 += wt * bf2f((ushort)v.z);
        a5 += wt * bf2f((ushort)(v.z >> 16));
        a6 += wt * bf2f((ushort)v.w);
        a7 += wt * bf2f((ushort)(v.w >> 16));
    }
    uint4 o;
    o.x = (uint32_t)f2bf(a0) | ((uint32_t)f2bf(a1) << 16);
    o.y = (uint32_t)f2bf(a2) | ((uint32_t)f2bf(a3) << 16);
    o.z = (uint32_t)f2bf(a4) | ((uint32_t)f2bf(a5) << 16);
    o.w = (uint32_t)f2bf(a6) | ((uint32_t)f2bf(a7) << 16);
    *(uint4*)(y + (size_t)n * ROWU + t * 8) = o;
}

// Fused GEMM + bias + LayerNorm, double-buffered (T3-minimum schedule).
// out = [A0|A1|A2] (bf16, node-major rows m'=n*8+b) @ WcatT^T, then per-row LN,
// with row un-permutation (m' -> b*N+n) in the epilogue.
// Tile: 128 rows x 256 cols (full C width -> row stats in-block), BK=32, 24 K-steps,
// 512 threads = 8 waves (2x4), wave tile 64x64 (4x4 mfma 16x16x32).
// Schedule per kt: STAGE(next buf) issued FIRST (async gload_lds), then
// ds_read+16 MFMA on current buf, then ONE barrier (drains vmcnt+lgkm).
// Stage latency hides under compute; barrier count halved vs 2-barrier form.
// LDS 2*(8+16)+4 = 52 KB -> 2 blocks/CU; K-loop live set ~100 VGPR < 128 cap.
#define STAGE(buf, kt_) do {                                                   \
    const ushort* ab_ = ((kt_) < 8) ? a0 : (((kt_) < 16) ? a1 : a2);           \
    const int kl_ = ((kt_) & 7) * 32;                                          \
    const int kg_ = (kt_) * 32;                                                \
    gload16(ab_ + (size_t)(row0 + (tid >> 2)) * CC + kl_ + (tid & 3) * 8,      \
            &As[buf][wid * 512]);                                              \
    gload16(wt + (size_t)(tid >> 2) * 768 + kg_ + (tid & 3) * 8,               \
            &Bs[buf][wid * 512]);                                              \
    gload16(wt + (size_t)((512 + tid) >> 2) * 768 + kg_ + (tid & 3) * 8,       \
            &Bs[buf][4096 + wid * 512]);                                       \
} while (0)

__global__ void __launch_bounds__(512, 4) gemmln_k(const ushort* __restrict__ a0,
                                                   const ushort* __restrict__ a1,
                                                   const ushort* __restrict__ a2,
                                                   const ushort* __restrict__ wt,
                                                   const float* __restrict__ bias,
                                                   const float* __restrict__ lnw,
                                                   const float* __restrict__ lnb,
                                                   float* __restrict__ out) {
    __shared__ ushort As[2][128 * 32];   // 2 x 8 KB
    __shared__ ushort Bs[2][256 * 32];   // 2 x 16 KB
    __shared__ float reds[128][4];       // per-row per-colwave partial sum
    __shared__ float redq[128][4];       // per-row per-colwave partial sumsq
    const int tid = threadIdx.x;
    const int wid = tid >> 6, lane = tid & 63;
    const int wrow = wid >> 2, wcol = wid & 3;
    const int quad = lane >> 4, l16 = lane & 15;
    const int row0 = blockIdx.x * 128;

    f32x4 acc[4][4] = {};

    STAGE(0, 0);
    __syncthreads();                     // drain prologue stage
    int cur = 0;
    for (int kt = 0; kt < 24; kt++) {
        if (kt < 23) STAGE(cur ^ 1, kt + 1);   // async prefetch into other buffer

        bf16x8 af[4], bfr[4];
#pragma unroll
        for (int mt = 0; mt < 4; mt++)
            af[mt] = *(const bf16x8*)&As[cur][(wrow * 64 + mt * 16 + l16) * 32 + quad * 8];
#pragma unroll
        for (int nt = 0; nt < 4; nt++)
            bfr[nt] = *(const bf16x8*)&Bs[cur][(wcol * 64 + nt * 16 + l16) * 32 + quad * 8];
#pragma unroll
        for (int mt = 0; mt < 4; mt++)
#pragma unroll
            for (int nt = 0; nt < 4; nt++)
                acc[mt][nt] = __builtin_amdgcn_mfma_f32_16x16x32_bf16(
                    af[mt], bfr[nt], acc[mt][nt], 0, 0, 0);

        __syncthreads();                 // drains vmcnt (next buf ready) + read fence
        cur ^= 1;
    }

    // ---- fused epilogue: bias + LayerNorm + un-permute + store ----
    // C/D layout: col = lane&15, row = (lane>>4)*4 + reg   [measured m89]
    // lane's cols: wcol*64 + nt*16 + l16, nt=0..3
    float bv[4], lwv[4], lbv[4];
#pragma unroll
    for (int nt = 0; nt < 4; nt++) {
        int c = wcol * 64 + nt * 16 + l16;
        bv[nt] = bias[c]; lwv[nt] = lnw[c]; lbv[nt] = lnb[c];
    }
    // per-row partial stats over this wave's 64 cols (reduce over l16 group)
#pragma unroll
    for (int mt = 0; mt < 4; mt++) {
#pragma unroll
        for (int r = 0; r < 4; r++) {
            float s = 0.0f, q = 0.0f;
#pragma unroll
            for (int nt = 0; nt < 4; nt++) {
                float v = acc[mt][nt][r] + bv[nt];
                s += v; q += v * v;
            }
#pragma unroll
            for (int off = 1; off < 16; off <<= 1) {
                s += __shfl_xor(s, off, 64);
                q += __shfl_xor(q, off, 64);
            }
            if (l16 == 0) {
                int ml = wrow * 64 + mt * 16 + quad * 4 + r;
                reds[ml][wcol] = s;
                redq[ml][wcol] = q;
            }
        }
    }
    __syncthreads();
#pragma unroll
    for (int mt = 0; mt < 4; mt++) {
#pragma unroll
        for (int r = 0; r < 4; r++) {
            int ml = wrow * 64 + mt * 16 + quad * 4 + r;
            float s = reds[ml][0] + reds[ml][1] + reds[ml][2] + reds[ml][3];
            float q = redq[ml][0] + redq[ml][1] + redq[ml][2] + redq[ml][3];
            float mean = s * (1.0f / CC);
            float var = q * (1.0f / CC) - mean * mean;
            float rs = rsqrtf(var + 1e-5f);
            int m = row0 + ml;
            int n = m >> 3, b = m & 7;
            size_t orow = (size_t)b * NN + n;
#pragma unroll
            for (int nt = 0; nt < 4; nt++) {
                int c = wcol * 64 + nt * 16 + l16;
                float v = (acc[mt][nt][r] + bv[nt] - mean) * rs * lwv[nt] + lbv[nt];
                out[orow * CC + c] = v;
            }
        }
    }
}

extern "C" void kernel_launch(void* const* d_in, const int* in_sizes, int n_in,
                              void* d_out, int out_size, void* d_ws, size_t ws_size,
                              hipStream_t stream) {
    const float* feats = (const float*)d_in[0];
    const float* W     = (const float*)d_in[1];   // [L,K,C,C]
    const float* bvec  = (const float*)d_in[2];   // [L,C]
    const float* lnw   = (const float*)d_in[3];   // [L,C]
    const float* lnb   = (const float*)d_in[4];   // [L,C]
    const int*   eidx  = (const int*)d_in[5];     // (2,E) int32 or int64 (detected)
    float* outp = (float*)d_out;

    // ---- workspace carve-up ----
    int* flag    = (int*)d_ws;            // 64 ints (only [0] used)
    int* deg_out = flag + 64;             // N
    int* cnt_in  = deg_out + NN;          // N
    int* fillc   = cnt_in + NN;           // N   (memset covers up to here)
    int* row_ptr = fillc + NN;            // N+1 (+pad)
    int* srcw    = row_ptr + (NN + 64);   // E
    int* dstw    = srcw + EE;             // E
    int2* cw     = (int2*)(dstw + EE);    // E  (8-B aligned: offset is even)
    float* disw  = (float*)(cw + EE);     // N (+pad)
    uintptr_t bf_base = ((uintptr_t)(disw + NN + 64) + 255) & ~(uintptr_t)255;
    ushort* featsb = (ushort*)bf_base;                 // M*C bf16  [n,b,c]
    ushort* tx1b   = featsb + (size_t)MROWS * CC;      // M*C
    ushort* p2b    = tx1b + (size_t)MROWS * CC;        // M*C
    ushort* wcat   = p2b + (size_t)MROWS * CC;         // 256*768

    hipMemsetAsync(flag, 0, (size_t)(64 + 3 * NN) * sizeof(int), stream);

    // host-side edge width detection from input byte size; device fallback if ambiguous
    int mode = 0;
    long long esz = in_sizes ? (long long)in_sizes[5] : 0;
    if (esz == (long long)2 * EE * 8) mode = 2;        // int64
    else if (esz == (long long)2 * EE * 4) mode = 1;   // int32

    int eb = (EE + 255) / 256;  // 1250
    if (mode == 0) detect_k<<<eb, 256, 0, stream>>>(eidx, flag);
    convcount_k<<<eb, 256, 0, stream>>>(eidx, flag, mode, srcw, dstw, deg_out, cnt_in);
    scan_k<<<1, 1024, 0, stream>>>(cnt_in, deg_out, row_ptr, disw);
    fill_k<<<eb, 256, 0, stream>>>(srcw, dstw, row_ptr, fillc, disw, cw);

    cvtwprep_k<<<MROWS * CC / 1024 + 768, 256, 0, stream>>>(feats, featsb, W, wcat);

    prop_k<<<NN, 256, 0, stream>>>(featsb, tx1b, row_ptr, cw);
    prop_k<<<NN, 256, 0, stream>>>(tx1b, p2b, row_ptr, cw);

    // fused GEMM + bias + LayerNorm (layer-1 params; layer-0 output is overwritten)
    gemmln_k<<<MROWS / 128, 512, 0, stream>>>(featsb, tx1b, p2b, wcat,
                                              bvec + CC, lnw + CC, lnb + CC, outp);
}

// Round 6
// 797.826 us; speedup vs baseline: 1.1421x; 1.1421x over previous
//
#include <hip/hip_runtime.h>
#include <stdint.h>

// Problem constants (fixed by reference)
#define BB 8
#define NN 20000
#define CC 256
#define EE 320000
#define KK 3
#define MROWS (BB * NN)   // 160000

// ---------- bf16 helpers (raw ushort representation) ----------
__device__ __forceinline__ float bf2f(ushort u) {
    union { uint32_t ui; float f; } v; v.ui = ((uint32_t)u) << 16; return v.f;
}
__device__ __forceinline__ ushort f2bf(float f) {
    union { uint32_t ui; float f; } v; v.f = f;
    uint32_t r = (v.ui + 0x7FFFu + ((v.ui >> 16) & 1u)) >> 16;
    return (ushort)r;
}

typedef __bf16 bf16x8 __attribute__((ext_vector_type(8)));
typedef float  f32x4  __attribute__((ext_vector_type(4)));

__device__ __forceinline__ void gload16(const void* gptr, void* lptr) {
    __builtin_amdgcn_global_load_lds(
        (const __attribute__((address_space(1))) void*)gptr,
        (__attribute__((address_space(3))) void*)lptr, 16, 0, 0);
}

// ---------- edge width detect (FALLBACK ONLY when in_sizes is ambiguous) ----------
__global__ void detect_k(const int* __restrict__ raw, int* __restrict__ flag) {
    int i = blockIdx.x * 256 + threadIdx.x;
    int v = 0;
    int idx = 2 * i + 1;
    if (i < EE) v = raw[idx];            // odd 32-bit word in [0, 2E)
    unsigned long long m = __ballot(v != 0);
    if ((threadIdx.x & 63) == 0 && m) atomicOr(flag, 1);
}

// FUSED: edge convert+count  |  fp32->bf16 linear downcast  |  WcatT prep
// blocks [0,1250):      normalize edges to int32 + degree counts
// blocks [1250,41250):  x bf16 downcast, layout [b][n][c] == input layout (linear)
// blocks [41250,42018): WcatT[n][k] bf16 (Tx2 = 2*P2 - Tx0 folded into weights)
__global__ void fusedpre_k(const int* __restrict__ raw, const int* __restrict__ flag,
                           int mode,
                           int* __restrict__ src, int* __restrict__ dst,
                           int* __restrict__ deg_out, int* __restrict__ cnt_in,
                           const float* __restrict__ xf, ushort* __restrict__ xb,
                           const float* __restrict__ W, ushort* __restrict__ wt) {
    int bid = blockIdx.x;
    if (bid < 1250) {
        int e = bid * 256 + threadIdx.x;
        if (e >= EE) return;
        int m = mode ? mode : (*flag ? 1 : 2);   // flag!=0 -> genuine int32 data
        int s, d;
        if (m == 2) { s = raw[2 * e]; d = raw[2 * EE + 2 * e]; }   // int64 low words
        else        { s = raw[e];     d = raw[EE + e]; }            // int32
        src[e] = s; dst[e] = d;
        atomicAdd(&deg_out[s], 1);
        atomicAdd(&cnt_in[d], 1);
    } else if (bid < 41250) {
        size_t idx = ((size_t)(bid - 1250) * 256 + threadIdx.x) * 4;
        float4 v = *(const float4*)(xf + idx);
        *(ushort4*)(xb + idx) = make_ushort4(f2bf(v.x), f2bf(v.y), f2bf(v.z), f2bf(v.w));
    } else {
        int idx = (bid - 41250) * 256 + threadIdx.x;
        if (idx >= 256 * 768) return;
        int n = idx / 768, k = idx % 768;
        int sel = k >> 8, kk = k & 255;
        const float* W1 = W + KK * CC * CC;  // layer 1
        float v;
        if (sel == 0)      v = W1[kk * CC + n] - W1[2 * CC * CC + kk * CC + n];
        else if (sel == 1) v = W1[CC * CC + kk * CC + n];
        else               v = 2.0f * W1[2 * CC * CC + kk * CC + n];
        wt[idx] = f2bf(v);
    }
}

// single-block scan, shfl-based: thread t owns 20 contiguous elements.
__global__ void __launch_bounds__(1024) scan_k(const int* __restrict__ cnt_in,
                                               const int* __restrict__ deg_out,
                                               int* __restrict__ row_ptr,
                                               float* __restrict__ dis) {
    __shared__ int wpart[16];
    const int t = threadIdx.x;
    const int lane = t & 63, wid = t >> 6;
    const int base = t * 20;
    int local[20];
    int sum = 0;
#pragma unroll
    for (int i = 0; i < 20; i++) {
        int idx = base + i;
        int v = (idx < NN) ? cnt_in[idx] : 0;
        local[i] = sum;
        sum += v;
    }
    int sc = sum;  // inclusive wave scan of per-thread sums
#pragma unroll
    for (int off = 1; off < 64; off <<= 1) {
        int u = __shfl_up(sc, off, 64);
        if (lane >= off) sc += u;
    }
    if (lane == 63) wpart[wid] = sc;
    __syncthreads();
    if (wid == 0 && lane < 16) {
        int v = wpart[lane];
#pragma unroll
        for (int off = 1; off < 16; off <<= 1) {
            int u = __shfl_up(v, off, 64);
            if (lane >= off) v += u;
        }
        wpart[lane] = v;
    }
    __syncthreads();
    int wbase = (wid > 0) ? wpart[wid - 1] : 0;
    int tbase = wbase + sc - sum;  // exclusive base for this thread
#pragma unroll
    for (int i = 0; i < 20; i++) {
        int idx = base + i;
        if (idx < NN) row_ptr[idx] = tbase + local[i];
    }
    if (t == 1023) row_ptr[NN] = tbase + sum;
    for (int i = t; i < NN; i += 1024) {
        int d = deg_out[i];
        dis[i] = (d > 0) ? rsqrtf((float)d) : 0.0f;
    }
}

// packed (col, weight-bits) per CSR slot: one 8-B store instead of two 4-B scatters
__global__ void fill_k(const int* __restrict__ src, const int* __restrict__ dst,
                       const int* __restrict__ row_ptr, int* __restrict__ fillc,
                       const float* __restrict__ dis,
                       int2* __restrict__ cw) {
    int e = blockIdx.x * 256 + threadIdx.x;
    if (e >= EE) return;
    int s = src[e], d = dst[e];
    int pos = row_ptr[d] + atomicAdd(&fillc[d], 1);
    cw[pos] = make_int2(s, __float_as_int(-dis[s] * dis[d]));
}

// Batch-major prop: y[b,n,:] = sum_{e: dst=n} w[e] * x[b, col[e], :]
// One WAVE per (dst, b): 64 lanes x 4 ch (uint2 = 8 B/lane, 512 B/row, coalesced).
// grid (NN/4, BB), x-fastest dispatch -> batch-phased execution: per-phase gather
// working set = one batch = 10 MB (vs 80 MB in node-major layout) -> cache-resident.
// Theory: R0-R5's FETCH=614 MB (47% of the 1.31 GB gather volume missing to memory
// on an 80 MB source) is a cache-capacity effect; 10 MB phases should collapse it.
__global__ void __launch_bounds__(256) prop_k(const ushort* __restrict__ x,
                                              ushort* __restrict__ y,
                                              const int* __restrict__ row_ptr,
                                              const int2* __restrict__ cw) {
    const int wavei = threadIdx.x >> 6;
    const int lane = threadIdx.x & 63;
    const int n = blockIdx.x * 4 + wavei;        // dst node
    const int b = blockIdx.y;                    // batch
    const size_t bbase = (size_t)b * NN * CC;
    const ushort* xb = x + bbase + lane * 4;     // lane's 4 channels
    const int beg = row_ptr[n], end = row_ptr[n + 1];
    float a0 = 0, a1 = 0, a2 = 0, a3 = 0;
    int j = beg;
    for (; j + 4 <= end; j += 4) {
        int2 e0 = cw[j], e1 = cw[j + 1], e2 = cw[j + 2], e3 = cw[j + 3];
        float w0 = __int_as_float(e0.y), w1 = __int_as_float(e1.y);
        float w2 = __int_as_float(e2.y), w3 = __int_as_float(e3.y);
        uint2 v0 = *(const uint2*)(xb + (size_t)e0.x * CC);
        uint2 v1 = *(const uint2*)(xb + (size_t)e1.x * CC);
        uint2 v2 = *(const uint2*)(xb + (size_t)e2.x * CC);
        uint2 v3 = *(const uint2*)(xb + (size_t)e3.x * CC);
        a0 += w0 * bf2f((ushort)v0.x) + w1 * bf2f((ushort)v1.x)
            + w2 * bf2f((ushort)v2.x) + w3 * bf2f((ushort)v3.x);
        a1 += w0 * bf2f((ushort)(v0.x >> 16)) + w1 * bf2f((ushort)(v1.x >> 16))
            + w2 * bf2f((ushort)(v2.x >> 16)) + w3 * bf2f((ushort)(v3.x >> 16));
        a2 += w0 * bf2f((ushort)v0.y) + w1 * bf2f((ushort)v1.y)
            + w2 * bf2f((ushort)v2.y) + w3 * bf2f((ushort)v3.y);
        a3 += w0 * bf2f((ushort)(v0.y >> 16)) + w1 * bf2f((ushort)(v1.y >> 16))
            + w2 * bf2f((ushort)(v2.y >> 16)) + w3 * bf2f((ushort)(v3.y >> 16));
    }
    for (; j < end; j++) {
        int2 e0 = cw[j];
        float wt = __int_as_float(e0.y);
        uint2 v = *(const uint2*)(xb + (size_t)e0.x * CC);
        a0 += wt * bf2f((ushort)v.x);
        a1 += wt * bf2f((ushort)(v.x >> 16));
        a2 += wt * bf2f((ushort)v.y);
        a3 += wt * bf2f((ushort)(v.y >> 16));
    }
    ushort4 o = make_ushort4(f2bf(a0), f2bf(a1), f2bf(a2), f2bf(a3));
    *(ushort4*)(y + bbase + (size_t)n * CC + lane * 4) = o;
}

// Fused GEMM + bias + LayerNorm, double-buffered.
// out = [A0|A1|A2] (bf16, rows m=b*N+n directly) @ WcatT^T, then per-row LN.
// b-major layout -> NO row un-permutation needed: out row = m.
// Tile: 128 rows x 256 cols (full C width -> row stats in-block), BK=32, 24 K-steps,
// 512 threads = 8 waves (2x4), wave tile 64x64 (4x4 mfma 16x16x32).
// Schedule-invariant at this size (BK64+swizzle and dbuf both measured null) ->
// memory/compute floor; keep the simple dbuf form.
#define STAGE(buf, kt_) do {                                                   \
    const ushort* ab_ = ((kt_) < 8) ? a0 : (((kt_) < 16) ? a1 : a2);           \
    const int kl_ = ((kt_) & 7) * 32;                                          \
    const int kg_ = (kt_) * 32;                                                \
    gload16(ab_ + (size_t)(row0 + (tid >> 2)) * CC + kl_ + (tid & 3) * 8,      \
            &As[buf][wid * 512]);                                              \
    gload16(wt + (size_t)(tid >> 2) * 768 + kg_ + (tid & 3) * 8,               \
            &Bs[buf][wid * 512]);                                              \
    gload16(wt + (size_t)((512 + tid) >> 2) * 768 + kg_ + (tid & 3) * 8,       \
            &Bs[buf][4096 + wid * 512]);                                       \
} while (0)

__global__ void __launch_bounds__(512, 4) gemmln_k(const ushort* __restrict__ a0,
                                                   const ushort* __restrict__ a1,
                                                   const ushort* __restrict__ a2,
                                                   const ushort* __restrict__ wt,
                                                   const float* __restrict__ bias,
                                                   const float* __restrict__ lnw,
                                                   const float* __restrict__ lnb,
                                                   float* __restrict__ out) {
    __shared__ ushort As[2][128 * 32];   // 2 x 8 KB
    __shared__ ushort Bs[2][256 * 32];   // 2 x 16 KB
    __shared__ float reds[128][4];       // per-row per-colwave partial sum
    __shared__ float redq[128][4];       // per-row per-colwave partial sumsq
    const int tid = threadIdx.x;
    const int wid = tid >> 6, lane = tid & 63;
    const int wrow = wid >> 2, wcol = wid & 3;
    const int quad = lane >> 4, l16 = lane & 15;
    const int row0 = blockIdx.x * 128;

    f32x4 acc[4][4] = {};

    STAGE(0, 0);
    __syncthreads();                     // drain prologue stage
    int cur = 0;
    for (int kt = 0; kt < 24; kt++) {
        if (kt < 23) STAGE(cur ^ 1, kt + 1);   // async prefetch into other buffer

        bf16x8 af[4], bfr[4];
#pragma unroll
        for (int mt = 0; mt < 4; mt++)
            af[mt] = *(const bf16x8*)&As[cur][(wrow * 64 + mt * 16 + l16) * 32 + quad * 8];
#pragma unroll
        for (int nt = 0; nt < 4; nt++)
            bfr[nt] = *(const bf16x8*)&Bs[cur][(wcol * 64 + nt * 16 + l16) * 32 + quad * 8];
#pragma unroll
        for (int mt = 0; mt < 4; mt++)
#pragma unroll
            for (int nt = 0; nt < 4; nt++)
                acc[mt][nt] = __builtin_amdgcn_mfma_f32_16x16x32_bf16(
                    af[mt], bfr[nt], acc[mt][nt], 0, 0, 0);

        __syncthreads();                 // drains vmcnt (next buf ready) + read fence
        cur ^= 1;
    }

    // ---- fused epilogue: bias + LayerNorm + store ----
    // C/D layout: col = lane&15, row = (lane>>4)*4 + reg   [measured m89]
    float bv[4], lwv[4], lbv[4];
#pragma unroll
    for (int nt = 0; nt < 4; nt++) {
        int c = wcol * 64 + nt * 16 + l16;
        bv[nt] = bias[c]; lwv[nt] = lnw[c]; lbv[nt] = lnb[c];
    }
#pragma unroll
    for (int mt = 0; mt < 4; mt++) {
#pragma unroll
        for (int r = 0; r < 4; r++) {
            float s = 0.0f, q = 0.0f;
#pragma unroll
            for (int nt = 0; nt < 4; nt++) {
                float v = acc[mt][nt][r] + bv[nt];
                s += v; q += v * v;
            }
#pragma unroll
            for (int off = 1; off < 16; off <<= 1) {
                s += __shfl_xor(s, off, 64);
                q += __shfl_xor(q, off, 64);
            }
            if (l16 == 0) {
                int ml = wrow * 64 + mt * 16 + quad * 4 + r;
                reds[ml][wcol] = s;
                redq[ml][wcol] = q;
            }
        }
    }
    __syncthreads();
#pragma unroll
    for (int mt = 0; mt < 4; mt++) {
#pragma unroll
        for (int r = 0; r < 4; r++) {
            int ml = wrow * 64 + mt * 16 + quad * 4 + r;
            float s = reds[ml][0] + reds[ml][1] + reds[ml][2] + reds[ml][3];
            float q = redq[ml][0] + redq[ml][1] + redq[ml][2] + redq[ml][3];
            float mean = s * (1.0f / CC);
            float var = q * (1.0f / CC) - mean * mean;
            float rs = rsqrtf(var + 1e-5f);
            size_t orow = (size_t)(row0 + ml);   // b-major: out row == A row
#pragma unroll
            for (int nt = 0; nt < 4; nt++) {
                int c = wcol * 64 + nt * 16 + l16;
                float v = (acc[mt][nt][r] + bv[nt] - mean) * rs * lwv[nt] + lbv[nt];
                out[orow * CC + c] = v;
            }
        }
    }
}

extern "C" void kernel_launch(void* const* d_in, const int* in_sizes, int n_in,
                              void* d_out, int out_size, void* d_ws, size_t ws_size,
                              hipStream_t stream) {
    const float* feats = (const float*)d_in[0];
    const float* W     = (const float*)d_in[1];   // [L,K,C,C]
    const float* bvec  = (const float*)d_in[2];   // [L,C]
    const float* lnw   = (const float*)d_in[3];   // [L,C]
    const float* lnb   = (const float*)d_in[4];   // [L,C]
    const int*   eidx  = (const int*)d_in[5];     // (2,E) int32 or int64 (detected)
    float* outp = (float*)d_out;

    // ---- workspace carve-up ----
    int* flag    = (int*)d_ws;            // 64 ints (only [0] used)
    int* deg_out = flag + 64;             // N
    int* cnt_in  = deg_out + NN;          // N
    int* fillc   = cnt_in + NN;           // N   (memset covers up to here)
    int* row_ptr = fillc + NN;            // N+1 (+pad)
    int* srcw    = row_ptr + (NN + 64);   // E
    int* dstw    = srcw + EE;             // E
    int2* cw     = (int2*)(dstw + EE);    // E  (8-B aligned: offset is even)
    float* disw  = (float*)(cw + EE);     // N (+pad)
    uintptr_t bf_base = ((uintptr_t)(disw + NN + 64) + 255) & ~(uintptr_t)255;
    ushort* featsb = (ushort*)bf_base;                 // M*C bf16  [b,n,c]
    ushort* tx1b   = featsb + (size_t)MROWS * CC;      // M*C
    ushort* p2b    = tx1b + (size_t)MROWS * CC;        // M*C
    ushort* wcat   = p2b + (size_t)MROWS * CC;         // 256*768

    hipMemsetAsync(flag, 0, (size_t)(64 + 3 * NN) * sizeof(int), stream);

    // host-side edge width detection from input byte size; device fallback if ambiguous
    int mode = 0;
    long long esz = in_sizes ? (long long)in_sizes[5] : 0;
    if (esz == (long long)2 * EE * 8) mode = 2;        // int64
    else if (esz == (long long)2 * EE * 4) mode = 1;   // int32

    int eb = (EE + 255) / 256;  // 1250
    if (mode == 0) detect_k<<<eb, 256, 0, stream>>>(eidx, flag);

    // fused: edge convert+count | bf16 downcast | weight prep  (42018 blocks)
    fusedpre_k<<<1250 + 40000 + 768, 256, 0, stream>>>(eidx, flag, mode,
                                                       srcw, dstw, deg_out, cnt_in,
                                                       feats, featsb, W, wcat);
    scan_k<<<1, 1024, 0, stream>>>(cnt_in, deg_out, row_ptr, disw);
    fill_k<<<eb, 256, 0, stream>>>(srcw, dstw, row_ptr, fillc, disw, cw);

    prop_k<<<dim3(NN / 4, BB), 256, 0, stream>>>(featsb, tx1b, row_ptr, cw);
    prop_k<<<dim3(NN / 4, BB), 256, 0, stream>>>(tx1b, p2b, row_ptr, cw);

    // fused GEMM + bias + LayerNorm (layer-1 params; layer-0 output is overwritten)
    gemmln_k<<<MROWS / 128, 512, 0, stream>>>(featsb, tx1b, p2b, wcat,
                                              bvec + CC, lnw + CC, lnb + CC, outp);
}